// Round 5
// baseline (628.838 us; speedup 1.0000x reference)
//
#include <hip/hip_runtime.h>
#include <math.h>

// Problem constants: B=32, T=1024, OBS=512, H=512, DI=1024, L=2, A=16
#define MROWS 32768   // B*T
#define T_LEN 1024

typedef __attribute__((ext_vector_type(8))) short bf16x8;
typedef __attribute__((ext_vector_type(4))) float f32x4;

__device__ __forceinline__ unsigned short f2bf(float f) {
  union { float f; unsigned u; } x; x.f = f;
  unsigned r = x.u + 0x7fffu + ((x.u >> 16) & 1u);   // RNE
  return (unsigned short)(r >> 16);
}
__device__ __forceinline__ float bf2f(unsigned short u) {
  union { unsigned u; float f; } x; x.u = ((unsigned)u) << 16; return x.f;
}

__device__ __forceinline__ void gload_lds16(const void* g, void* l) {
  __builtin_amdgcn_global_load_lds(
      (const __attribute__((address_space(1))) void*)g,
      (__attribute__((address_space(3))) void*)l, 16, 0, 0);
}

// fast sigmoid via v_rcp_f32 (1 ulp; invisible under bf16 RNE rounding).
// rcp(1+exp(x)) form is overflow-safe at both ends (no inf*0 NaN corner).
__device__ __forceinline__ float sigm_neg(float x) {   // sigmoid(-x)
  return __builtin_amdgcn_rcpf(1.0f + __expf(x));
}

// ---------------------------------------------------------------------------
// GEMM: C[M,N] = A[M,(lda)] (bf16, K cols used) * B[N,K]^T (bf16), fp32 accum.
// MODE 0: += bias[n] (f32), exact GELU, write bf16
// MODE 1: write bf16
// MODE 2: += res[m,n] (bf16, may alias outb), write bf16
// MODE 3: minGRU gate transform fused into epilogue (hg GEMM, N=2048):
//         n>=1024 (gate g):  write a = sigmoid(-g)   [scan uses z = 1-a]
//         n< 1024 (hidden):  write G = g(hid) = hid>=0 ? hid+0.5 : sigmoid(hid)
//         R14 lesson: 1.0f/(1+e) compiles to the exact-div sequence (~35
//         VALU/elem, +14us/dispatch). R15 uses v_rcp_f32 (~4 VALU/elem).
//
// Structure = R0's proven kernel (m97-structure, ~810-900 TF; R11-R13 256^2
// experiments regressed: coarse phases at 1 block/CU serialize on the
// barrier drain — this structure's cover is multi-block TLP, m114).
// Tiles: BM=BN=128, BK=64; 4 waves; each wave 64x64 via 4x4 MFMA 16x16x32,
// two kh half-steps per K-tile. XOR-swizzled LDS (slot = chunk ^ (row&7)),
// measured 0 bank conflicts.
// R15 grid order: blockIdx.x = n-tile (fastest), blockIdx.y = m-tile, so
// consecutive blocks share one 256KB A m-panel (read ~once from HBM; R14
// m-fastest order re-streamed 32MB A per n-sweep: FETCH 121MB vs ~40 ideal).
// ---------------------------------------------------------------------------
template<int MODE>
__global__ __launch_bounds__(256, 2)
void gemm_bt(const unsigned short* __restrict__ A, int lda,
             const unsigned short* __restrict__ B,
             int N, int K,
             const float* __restrict__ bias,
             const unsigned short* res,
             unsigned short* outb)
{
  __shared__ __align__(16) unsigned short sA[128 * 64];
  __shared__ __align__(16) unsigned short sB[128 * 64];
  const int tid  = threadIdx.x;
  const int wave = tid >> 6, lane = tid & 63;
  const int m0 = blockIdx.y * 128, n0 = blockIdx.x * 128;
  // staging: instr j = wave*4+i covers rows j*8..j*8+7 (8 rows x 8 chunks)
  const int srow   = lane >> 3;                   // row within 8-row group
  const int sslotb = ((lane & 7) ^ srow) * 16;    // swizzled source chunk (bytes)
  const int wm = wave & 1, wn = wave >> 1;
  const int r16 = lane & 15, q = lane >> 4;

  f32x4 acc[4][4];
#pragma unroll
  for (int i = 0; i < 4; i++)
#pragma unroll
    for (int j = 0; j < 4; j++)
#pragma unroll
      for (int e = 0; e < 4; e++) acc[i][j][e] = 0.0f;

  const char* Ab = (const char*)A;
  const char* Bb = (const char*)B;
  char* sAb = (char*)sA;
  char* sBb = (char*)sB;

  for (int kt = 0; kt < K; kt += 64) {
#pragma unroll
    for (int i = 0; i < 4; i++) {
      const int j = wave * 4 + i;
      const int row = j * 8 + srow;
      gload_lds16(Ab + ((size_t)(m0 + row) * lda + kt) * 2 + sslotb, sAb + j * 1024);
      gload_lds16(Bb + ((size_t)(n0 + row) * K   + kt) * 2 + sslotb, sBb + j * 1024);
    }
    __syncthreads();
#pragma unroll
    for (int kh = 0; kh < 2; kh++) {
      bf16x8 af[4], bfr[4];
#pragma unroll
      for (int mt = 0; mt < 4; mt++) {
        const int row = wm * 64 + mt * 16 + r16;
        af[mt] = *(const bf16x8*)(sAb + row * 128 + ((((kh << 2) | q) ^ (row & 7)) * 16));
      }
#pragma unroll
      for (int nt = 0; nt < 4; nt++) {
        const int row = wn * 64 + nt * 16 + r16;
        bfr[nt] = *(const bf16x8*)(sBb + row * 128 + ((((kh << 2) | q) ^ (row & 7)) * 16));
      }
#pragma unroll
      for (int mt = 0; mt < 4; mt++)
#pragma unroll
        for (int nt = 0; nt < 4; nt++)
          acc[mt][nt] = __builtin_amdgcn_mfma_f32_16x16x32_bf16(af[mt], bfr[nt], acc[mt][nt], 0, 0, 0);
    }
    __syncthreads();
  }

  // epilogue; C/D layout: n = lane&15, m = (lane>>4)*4 + r
  const bool isgate = (MODE == 3) && (n0 >= 1024);   // block-uniform (BN=128 | 1024)
#pragma unroll
  for (int mt = 0; mt < 4; mt++) {
#pragma unroll
    for (int nt = 0; nt < 4; nt++) {
#pragma unroll
      for (int r = 0; r < 4; r++) {
        const int m = m0 + wm * 64 + mt * 16 + q * 4 + r;
        const int n = n0 + wn * 64 + nt * 16 + r16;
        const size_t idx = (size_t)m * N + n;
        float v = acc[mt][nt][r];
        if (MODE == 0) {
          v += bias[n];
          v = 0.5f * v * (1.0f + erff(v * 0.70710678118654752f));
        } else if (MODE == 2) {
          v += bf2f(res[idx]);
        } else if (MODE == 3) {
          if (isgate) {
            v = sigm_neg(v);                  // a = sigmoid(-gate)
          } else {
            v = (v >= 0.0f) ? (v + 0.5f) : sigm_neg(-v);   // G = g(hidden)
          }
        }
        outb[idx] = f2bf(v);
      }
    }
  }
}

// ---------------------------------------------------------------------------
// minGRU chunked parallel scan, LDS-cache variant, pure-FMA pass 1.
// History: register caches always spill (R3/R4/R9/R10); recompute (R6,
// 86.6us) is VALU-bound at 77%. LDS caching of (a,b) works (R10). R14: the
// transcendentals moved into the hg-GEMM epilogue (MODE 3): hg holds
// G = g(hid) in the hidden slot and a = sigmoid(-gate) in the gate slot.
// Pass 1 is pure FMA: b = (1-a)*G  (z = sigmoid(gate) = 1-a), cached
// bf16-packed in LDS; pass 3 replays pure-FMA from LDS. T processed in 4
// segments of 256: cache 256 x 16dp x 8B = 32KB (+4KB summaries -> 4
// blocks/CU); inter-segment carry in registers of lanes tid<32.
//   h_t = a_t*h_{t-1} + b_t
// hg: [M, 2048] bf16 (G | a); h_t written over the a slot (same-thread
// read-before-write; replay reads a from LDS). Block = (batch b, 32 d's)
// = 256 threads = 16 chunks x 16 d-pairs, 16 t per chunk per segment.
// ---------------------------------------------------------------------------
__global__ __launch_bounds__(256)
void scan_kernel(unsigned short* hg) {
  __shared__ unsigned long long sAB[256 * 16];   // [t_local][dp]: lo=a-pair, hi=b-pair
  __shared__ float sA[16 * 32];                  // [chunk][d]: A-prod, then carry
  __shared__ float sH[16 * 32];                  // [chunk][d]: local scan sum
  const int b  = blockIdx.x >> 5;      // batch
  const int dg = blockIdx.x & 31;      // 32-d group
  const int tid = threadIdx.x;
  const int c  = tid >> 4;             // chunk 0..15
  const int dp = tid & 15;             // d-pair 0..15
  unsigned int* base = (unsigned int*)(hg + (size_t)b * T_LEN * 2048);
  const int du = dg * 16 + dp;         // u32 col of this thread's d-pair

  float carry = 0.0f;                  // per-d carry, lanes tid<32 only

  for (int seg = 0; seg < 4; ++seg) {
    const int t0 = seg * 256 + c * 16;

    // pass 1: pure FMA — read (G, a), form b=(1-a)*G, cache, chunk summary
    float A0 = 1.0f, A1 = 1.0f, h0 = 0.0f, h1 = 0.0f;
#pragma unroll
    for (int tl = 0; tl < 16; ++tl) {
      const int t = t0 + tl;
      const unsigned Gp  = base[t * 1024 + du];        // g(hid) pair (bf16)
      const unsigned apk = base[t * 1024 + 512 + du];  // a pair (bf16)
      const float G0  = bf2f((unsigned short)Gp),  G1  = bf2f((unsigned short)(Gp >> 16));
      const float fa0 = bf2f((unsigned short)apk), fa1 = bf2f((unsigned short)(apk >> 16));
      const unsigned short rb0 = f2bf((1.0f - fa0) * G0);
      const unsigned short rb1 = f2bf((1.0f - fa1) * G1);
      sAB[(c * 16 + tl) * 16 + dp] =
          (unsigned long long)apk |
          ((unsigned long long)((unsigned)rb0 | ((unsigned)rb1 << 16)) << 32);
      const float fb0 = bf2f(rb0), fb1 = bf2f(rb1);
      A0 *= fa0; h0 = fa0 * h0 + fb0;
      A1 *= fa1; h1 = fa1 * h1 + fb1;
    }
    sA[c * 32 + 2 * dp] = A0;  sA[c * 32 + 2 * dp + 1] = A1;
    sH[c * 32 + 2 * dp] = h0;  sH[c * 32 + 2 * dp + 1] = h1;
    __syncthreads();

    // pass 2: serial carry composition (one lane per d); overwrite sA w/ carry
    if (tid < 32) {
      float hin = carry;
#pragma unroll
      for (int cc = 0; cc < 16; ++cc) {
        const float a  = sA[cc * 32 + tid];
        const float hs = sH[cc * 32 + tid];
        sA[cc * 32 + tid] = hin;
        hin = hs + a * hin;
      }
      carry = hin;
    }
    __syncthreads();

    // pass 3: pure-FMA replay from LDS; write h over the a slot
    float hh0 = sA[c * 32 + 2 * dp];
    float hh1 = sA[c * 32 + 2 * dp + 1];
#pragma unroll
    for (int tl = 0; tl < 16; ++tl) {
      const int t = t0 + tl;
      const unsigned long long ab = sAB[(c * 16 + tl) * 16 + dp];
      const float fa0 = bf2f((unsigned short)ab);
      const float fa1 = bf2f((unsigned short)(ab >> 16));
      const float fb0 = bf2f((unsigned short)(ab >> 32));
      const float fb1 = bf2f((unsigned short)(ab >> 48));
      hh0 = fa0 * hh0 + fb0;
      hh1 = fa1 * hh1 + fb1;
      base[t * 1024 + 512 + du] = (unsigned)f2bf(hh0) | ((unsigned)f2bf(hh1) << 16);
    }
    __syncthreads();   // sAB/sA/sH reused next segment
  }
}

// ---------------------------------------------------------------------------
// RMSNorm in place on bf16 h. One wave per row of 512.
// ---------------------------------------------------------------------------
__global__ __launch_bounds__(256)
void rms_kernel(unsigned short* __restrict__ hb, const float* __restrict__ w) {
  const int wid  = (blockIdx.x * blockDim.x + threadIdx.x) >> 6;
  const int lane = threadIdx.x & 63;
  unsigned short* row = hb + (size_t)wid * 512;
  float v[8];
  float ss = 0.0f;
#pragma unroll
  for (int j = 0; j < 8; j++) { v[j] = bf2f(row[lane + 64 * j]); ss += v[j] * v[j]; }
#pragma unroll
  for (int off = 32; off >= 1; off >>= 1) ss += __shfl_xor(ss, off, 64);
  const float r = rsqrtf(ss * (1.0f / 512.0f) + 1.1920929e-7f);
#pragma unroll
  for (int j = 0; j < 8; j++) {
    const int k = lane + 64 * j;
    row[k] = f2bf(v[j] * r * w[k]);
  }
}

// ---------------------------------------------------------------------------
// Decoder: logits[row,16] = h.dec_w^T + dec_b; values[row] = h.val_w + val_b.
// ---------------------------------------------------------------------------
__global__ __launch_bounds__(256)
void decoder_kernel(const unsigned short* __restrict__ hb,
                    const float* __restrict__ dec_w,
                    const float* __restrict__ dec_b,
                    const float* __restrict__ val_w,
                    const float* __restrict__ val_b,
                    float* __restrict__ out) {
  const int nw   = (gridDim.x * blockDim.x) >> 6;
  const int wid  = (blockIdx.x * blockDim.x + threadIdx.x) >> 6;
  const int lane = threadIdx.x & 63;
  float* logits = out;
  float* values = out + (size_t)MROWS * 16;
  for (int row = wid; row < MROWS; row += nw) {
    const unsigned short* hr = hb + (size_t)row * 512;
    float acc[17];
#pragma unroll
    for (int a = 0; a < 17; a++) acc[a] = 0.0f;
#pragma unroll
    for (int j = 0; j < 8; j++) {
      const int k = lane + 64 * j;
      const float hv = bf2f(hr[k]);
#pragma unroll
      for (int a = 0; a < 16; a++) acc[a] += hv * dec_w[a * 512 + k];
      acc[16] += hv * val_w[k];
    }
#pragma unroll
    for (int a = 0; a < 17; a++) {
#pragma unroll
      for (int off = 32; off >= 1; off >>= 1) acc[a] += __shfl_xor(acc[a], off, 64);
    }
    if (lane == 0) {
#pragma unroll
      for (int a = 0; a < 16; a++) logits[(size_t)row * 16 + a] = acc[a] + dec_b[a];
      values[row] = acc[16] + val_b[0];
    }
  }
}

// ---------------------------------------------------------------------------
__global__ __launch_bounds__(256)
void conv_bf16(const float* __restrict__ in, unsigned short* __restrict__ out, int n4) {
  const int i = blockIdx.x * blockDim.x + threadIdx.x;
  if (i < n4) {
    const float4 v = ((const float4*)in)[i];
    const unsigned long long pack =
        (unsigned long long)f2bf(v.x) |
        ((unsigned long long)f2bf(v.y) << 16) |
        ((unsigned long long)f2bf(v.z) << 32) |
        ((unsigned long long)f2bf(v.w) << 48);
    ((unsigned long long*)out)[i] = pack;
  }
}

// ---------------------------------------------------------------------------
// Workspace layout (bytes) — total 174,587,904 (~166.5 MiB):
//   hg   bf16 [32768,2048] @ 0          (128 MB)  [xb bf16 aliases @0 pre-encoder]
//   hb   bf16 [32768,512]  @ 134217728  (32 MB)
//   wbf  bf16 weights      @ 167772160  (~6.5 MB)
// ---------------------------------------------------------------------------
extern "C" void kernel_launch(void* const* d_in, const int* in_sizes, int n_in,
                              void* d_out, int out_size, void* d_ws, size_t ws_size,
                              hipStream_t stream) {
  const float* x     = (const float*)d_in[0];
  const float* enc_w = (const float*)d_in[1];
  const float* enc_b = (const float*)d_in[2];
  const float* w_hg  = (const float*)d_in[3];
  const float* w_out = (const float*)d_in[4];
  const float* rms_w = (const float*)d_in[5];
  const float* dec_w = (const float*)d_in[6];
  const float* dec_b = (const float*)d_in[7];
  const float* val_w = (const float*)d_in[8];
  const float* val_b = (const float*)d_in[9];
  float* out = (float*)d_out;

  if (ws_size < 174587904u) return;  // fail loudly via absmax, not via fault

  char* ws = (char*)d_ws;
  unsigned short* hg   = (unsigned short*)(ws);
  unsigned short* xb   = (unsigned short*)(ws);               // alias (encoder only)
  unsigned short* hb   = (unsigned short*)(ws + 134217728);
  unsigned short* wenc = (unsigned short*)(ws + 167772160);
  unsigned short* whg  = wenc + 262144;                       // 2 layers x 2048x512
  unsigned short* wout = whg + 2097152;                       // 2 layers x 512x1024

  // bf16 conversions (x + all matmul weights)
  conv_bf16<<<16384, 256, 0, stream>>>(x, xb, 4194304);
  conv_bf16<<<256,   256, 0, stream>>>(enc_w, wenc, 65536);
  conv_bf16<<<2048,  256, 0, stream>>>(w_hg, whg, 524288);
  conv_bf16<<<1024,  256, 0, stream>>>(w_out, wout, 262144);

  // encoder: hb = gelu(x @ enc_w^T + enc_b); grid = (n-tiles, m-tiles)
  gemm_bt<0><<<dim3(4, 256), 256, 0, stream>>>(xb, 512, wenc, 512, 512, enc_b, nullptr, hb);

  for (int l = 0; l < 2; ++l) {
    // hg = transform(hb @ w_hg^T)  [M, 2048]: G in hidden half, a in gate half
    gemm_bt<3><<<dim3(16, 256), 256, 0, stream>>>(hb, 512, whg + (size_t)l * 1048576, 2048, 512,
                                                  nullptr, nullptr, hg);
    // LDS-cached chunked parallel scan (pure FMA): writes h over the a half
    scan_kernel<<<1024, 256, 0, stream>>>(hg);
    // hb = h(@hg+1024, lda 2048) @ w_out^T + hb  (bf16 residual, in place)
    gemm_bt<2><<<dim3(4, 256), 256, 0, stream>>>(hg + 1024, 2048, wout + (size_t)l * 524288,
                                                 512, 1024, nullptr, hb, hb);
    // RMSNorm in place
    rms_kernel<<<8192, 256, 0, stream>>>(hb, rms_w + (size_t)l * 512);
  }

  decoder_kernel<<<512, 256, 0, stream>>>(hb, dec_w, dec_b, val_w, val_b, out);
}

// Round 6
// 603.820 us; speedup vs baseline: 1.0414x; 1.0414x over previous
//
#include <hip/hip_runtime.h>
#include <math.h>

// Problem constants: B=32, T=1024, OBS=512, H=512, DI=1024, L=2, A=16
#define MROWS 32768   // B*T
#define T_LEN 1024

typedef __attribute__((ext_vector_type(8))) short bf16x8;
typedef __attribute__((ext_vector_type(4))) float f32x4;

__device__ __forceinline__ unsigned short f2bf(float f) {
  union { float f; unsigned u; } x; x.f = f;
  unsigned r = x.u + 0x7fffu + ((x.u >> 16) & 1u);   // RNE
  return (unsigned short)(r >> 16);
}
__device__ __forceinline__ float bf2f(unsigned short u) {
  union { unsigned u; float f; } x; x.u = ((unsigned)u) << 16; return x.f;
}

__device__ __forceinline__ void gload_lds16(const void* g, void* l) {
  __builtin_amdgcn_global_load_lds(
      (const __attribute__((address_space(1))) void*)g,
      (__attribute__((address_space(3))) void*)l, 16, 0, 0);
}

// fast sigmoid via v_rcp_f32 (1 ulp; invisible under bf16 RNE rounding).
// rcp(1+exp(x)) form is overflow-safe at both ends (no inf*0 NaN corner).
// R14 lesson: 1.0f/(1+e) compiles to the exact-div sequence (~35 VALU/elem).
__device__ __forceinline__ float sigm_neg(float x) {   // sigmoid(-x)
  return __builtin_amdgcn_rcpf(1.0f + __expf(x));
}

// ---------------------------------------------------------------------------
// GEMM: C[M,N] = A[M,(lda)] (bf16, K cols used) * B[N,K]^T (bf16), fp32 accum.
// N=512 (4 n-tiles) fixed for both users.
// MODE 0: += bias[n] (f32), exact GELU, write bf16   (encoder)
// MODE 2: += res[m,n] (bf16, may alias outb), write bf16  (out-proj)
//
// Structure = R0's proven m97-structure kernel (R11-R13 256^2 schedule
// experiments regressed; this structure's latency cover is multi-block TLP).
// Tiles: BM=BN=128, BK=64; 4 waves; each wave 64x64 via 4x4 MFMA 16x16x32,
// two kh half-steps per K-tile. XOR-swizzled LDS (slot = chunk ^ (row&7)),
// measured 0 bank conflicts.
// R16: 1-D grid + XCD-bijective swizzle (R15 lesson: consecutive blockIdx
// round-robin across XCDs, so source-order locality alone does nothing —
// the swizzle gives each XCD a contiguous chunk; n-inner within the chunk
// so the 4 n-blocks of one A m-panel run consecutively on ONE XCD's L2).
// ---------------------------------------------------------------------------
template<int MODE>
__global__ __launch_bounds__(256, 2)
void gemm_bt(const unsigned short* __restrict__ A, int lda,
             const unsigned short* __restrict__ B,
             int N, int K,
             const float* __restrict__ bias,
             const unsigned short* res,
             unsigned short* outb)
{
  __shared__ __align__(16) unsigned short sA[128 * 64];
  __shared__ __align__(16) unsigned short sB[128 * 64];
  const int tid  = threadIdx.x;
  const int wave = tid >> 6, lane = tid & 63;
  const int lid = blockIdx.x;
  const int swz = (lid & 7) * ((int)gridDim.x >> 3) + (lid >> 3);
  const int m0 = (swz >> 2) * 128;     // 4 n-tiles, n-inner
  const int n0 = (swz & 3) * 128;
  // staging: instr j = wave*4+i covers rows j*8..j*8+7 (8 rows x 8 chunks)
  const int srow   = lane >> 3;                   // row within 8-row group
  const int sslotb = ((lane & 7) ^ srow) * 16;    // swizzled source chunk (bytes)
  const int wm = wave & 1, wn = wave >> 1;
  const int r16 = lane & 15, q = lane >> 4;

  f32x4 acc[4][4];
#pragma unroll
  for (int i = 0; i < 4; i++)
#pragma unroll
    for (int j = 0; j < 4; j++)
#pragma unroll
      for (int e = 0; e < 4; e++) acc[i][j][e] = 0.0f;

  const char* Ab = (const char*)A;
  const char* Bb = (const char*)B;
  char* sAb = (char*)sA;
  char* sBb = (char*)sB;

  for (int kt = 0; kt < K; kt += 64) {
#pragma unroll
    for (int i = 0; i < 4; i++) {
      const int j = wave * 4 + i;
      const int row = j * 8 + srow;
      gload_lds16(Ab + ((size_t)(m0 + row) * lda + kt) * 2 + sslotb, sAb + j * 1024);
      gload_lds16(Bb + ((size_t)(n0 + row) * K   + kt) * 2 + sslotb, sBb + j * 1024);
    }
    __syncthreads();
#pragma unroll
    for (int kh = 0; kh < 2; kh++) {
      bf16x8 af[4], bfr[4];
#pragma unroll
      for (int mt = 0; mt < 4; mt++) {
        const int row = wm * 64 + mt * 16 + r16;
        af[mt] = *(const bf16x8*)(sAb + row * 128 + ((((kh << 2) | q) ^ (row & 7)) * 16));
      }
#pragma unroll
      for (int nt = 0; nt < 4; nt++) {
        const int row = wn * 64 + nt * 16 + r16;
        bfr[nt] = *(const bf16x8*)(sBb + row * 128 + ((((kh << 2) | q) ^ (row & 7)) * 16));
      }
#pragma unroll
      for (int mt = 0; mt < 4; mt++)
#pragma unroll
        for (int nt = 0; nt < 4; nt++)
          acc[mt][nt] = __builtin_amdgcn_mfma_f32_16x16x32_bf16(af[mt], bfr[nt], acc[mt][nt], 0, 0, 0);
    }
    __syncthreads();
  }

  // epilogue; C/D layout: n = lane&15, m = (lane>>4)*4 + r
#pragma unroll
  for (int mt = 0; mt < 4; mt++) {
#pragma unroll
    for (int nt = 0; nt < 4; nt++) {
#pragma unroll
      for (int r = 0; r < 4; r++) {
        const int m = m0 + wm * 64 + mt * 16 + q * 4 + r;
        const int n = n0 + wn * 64 + nt * 16 + r16;
        const size_t idx = (size_t)m * N + n;
        float v = acc[mt][nt][r];
        if (MODE == 0) {
          v += bias[n];
          v = 0.5f * v * (1.0f + erff(v * 0.70710678118654752f));
        } else if (MODE == 2) {
          v += bf2f(res[idx]);
        }
        outb[idx] = f2bf(v);
      }
    }
  }
}

// ---------------------------------------------------------------------------
// hg GEMM with paired hidden/gate columns + fused minGRU gate transform.
// One block computes hidden cols [128j,128j+128) AND gate cols +1024 from
// the SAME A LDS tile (A global traffic per output halves; MFMA:stage ratio
// 32:8 -> 64:12). Since hidden & gate for a given d live in the same
// thread, the epilogue emits the scan's operands directly:
//   a = sigmoid(-gate)            -> gate slot   [m, 1024+d]
//   b = (1-a) * g(hidden)         -> hidden slot [m, d]
// making scan pass-1 pure load+FMA. LDS 48KB (A + B0 + B1), 2 blocks/CU.
// Same m97 inner structure, same XOR swizzle, XCD-bijective n-inner grid
// (nwg=2048: each XCD chunk = 32 m-panels x 8 j, A panel L2-hot across its
// 8 consecutive same-XCD blocks).
// ---------------------------------------------------------------------------
__global__ __launch_bounds__(256, 2)
void gemm_hg(const unsigned short* __restrict__ A,    // hb [M,512]
             const unsigned short* __restrict__ B,    // whg layer [2048,512]
             unsigned short* __restrict__ outb)       // hg [M,2048]
{
  __shared__ __align__(16) unsigned short sA [128 * 64];
  __shared__ __align__(16) unsigned short sB0[128 * 64];
  __shared__ __align__(16) unsigned short sB1[128 * 64];
  const int tid  = threadIdx.x;
  const int wave = tid >> 6, lane = tid & 63;
  const int lid = blockIdx.x;
  const int swz = (lid & 7) * 256 + (lid >> 3);   // nwg = 2048
  const int m0  = (swz >> 3) * 128;               // 256 m-tiles
  const int nh0 = (swz & 7) * 128;                // hidden col base (gate = +1024)
  const int srow   = lane >> 3;
  const int sslotb = ((lane & 7) ^ srow) * 16;
  const int wm = wave & 1, wn = wave >> 1;
  const int r16 = lane & 15, q = lane >> 4;

  f32x4 acc0[4][4], acc1[4][4];
#pragma unroll
  for (int i = 0; i < 4; i++)
#pragma unroll
    for (int j = 0; j < 4; j++)
#pragma unroll
      for (int e = 0; e < 4; e++) { acc0[i][j][e] = 0.0f; acc1[i][j][e] = 0.0f; }

  const char* Ab = (const char*)A;
  const char* Bb = (const char*)B;
  char* sAb  = (char*)sA;
  char* sB0b = (char*)sB0;
  char* sB1b = (char*)sB1;

  for (int kt = 0; kt < 512; kt += 64) {
#pragma unroll
    for (int i = 0; i < 4; i++) {
      const int j = wave * 4 + i;
      const int row = j * 8 + srow;
      gload_lds16(Ab + ((size_t)(m0 + row) * 512 + kt) * 2 + sslotb, sAb + j * 1024);
      gload_lds16(Bb + ((size_t)(nh0 + row) * 512 + kt) * 2 + sslotb, sB0b + j * 1024);
      gload_lds16(Bb + ((size_t)(1024 + nh0 + row) * 512 + kt) * 2 + sslotb, sB1b + j * 1024);
    }
    __syncthreads();
#pragma unroll
    for (int kh = 0; kh < 2; kh++) {
      bf16x8 af[4], b0r[4], b1r[4];
#pragma unroll
      for (int mt = 0; mt < 4; mt++) {
        const int row = wm * 64 + mt * 16 + r16;
        af[mt] = *(const bf16x8*)(sAb + row * 128 + ((((kh << 2) | q) ^ (row & 7)) * 16));
      }
#pragma unroll
      for (int nt = 0; nt < 4; nt++) {
        const int row = wn * 64 + nt * 16 + r16;
        const int so  = ((((kh << 2) | q) ^ (row & 7)) * 16);
        b0r[nt] = *(const bf16x8*)(sB0b + row * 128 + so);
        b1r[nt] = *(const bf16x8*)(sB1b + row * 128 + so);
      }
#pragma unroll
      for (int mt = 0; mt < 4; mt++)
#pragma unroll
        for (int nt = 0; nt < 4; nt++) {
          acc0[mt][nt] = __builtin_amdgcn_mfma_f32_16x16x32_bf16(af[mt], b0r[nt], acc0[mt][nt], 0, 0, 0);
          acc1[mt][nt] = __builtin_amdgcn_mfma_f32_16x16x32_bf16(af[mt], b1r[nt], acc1[mt][nt], 0, 0, 0);
        }
    }
    __syncthreads();
  }

  // epilogue: emit b (hidden slot) and a (gate slot)
#pragma unroll
  for (int mt = 0; mt < 4; mt++) {
#pragma unroll
    for (int nt = 0; nt < 4; nt++) {
#pragma unroll
      for (int r = 0; r < 4; r++) {
        const int m  = m0 + wm * 64 + mt * 16 + q * 4 + r;
        const int d  = nh0 + wn * 64 + nt * 16 + r16;
        const float vh = acc0[mt][nt][r];
        const float vg = acc1[mt][nt][r];
        const float G = (vh >= 0.0f) ? (vh + 0.5f) : sigm_neg(-vh);
        const float a = sigm_neg(vg);
        const float b = (1.0f - a) * G;
        const size_t base = (size_t)m * 2048 + d;
        outb[base]        = f2bf(b);
        outb[base + 1024] = f2bf(a);
      }
    }
  }
}

// ---------------------------------------------------------------------------
// minGRU chunked parallel scan, LDS-cache variant, pure load+FMA pass 1.
// hg now holds b in the hidden slot and a in the gate slot (gemm_hg
// epilogue). h_t = a_t*h_{t-1} + b_t. Pass 1 caches (a,b) bf16-packed in
// LDS + chunk summaries; pass 2 serial carry; pass 3 pure-FMA replay,
// h written over the a slot (replay reads a from LDS). 4 segments of 256:
// cache 32KB + 4KB summaries -> 4 blocks/CU. Block = (batch, 32 d's) =
// 16 chunks x 16 d-pairs.
// ---------------------------------------------------------------------------
__global__ __launch_bounds__(256)
void scan_kernel(unsigned short* hg) {
  __shared__ unsigned long long sAB[256 * 16];   // [t_local][dp]: lo=a-pair, hi=b-pair
  __shared__ float sA[16 * 32];                  // [chunk][d]: A-prod, then carry
  __shared__ float sH[16 * 32];                  // [chunk][d]: local scan sum
  const int b  = blockIdx.x >> 5;      // batch
  const int dg = blockIdx.x & 31;      // 32-d group
  const int tid = threadIdx.x;
  const int c  = tid >> 4;             // chunk 0..15
  const int dp = tid & 15;             // d-pair 0..15
  unsigned int* base = (unsigned int*)(hg + (size_t)b * T_LEN * 2048);
  const int du = dg * 16 + dp;         // u32 col of this thread's d-pair

  float carry = 0.0f;                  // per-d carry, lanes tid<32 only

  for (int seg = 0; seg < 4; ++seg) {
    const int t0 = seg * 256 + c * 16;

    // pass 1: read (b, a), cache packed, accumulate chunk summary
    float A0 = 1.0f, A1 = 1.0f, h0 = 0.0f, h1 = 0.0f;
#pragma unroll
    for (int tl = 0; tl < 16; ++tl) {
      const int t = t0 + tl;
      const unsigned bpk = base[t * 1024 + du];        // b pair (hidden slot)
      const unsigned apk = base[t * 1024 + 512 + du];  // a pair (gate slot)
      sAB[(c * 16 + tl) * 16 + dp] =
          (unsigned long long)apk | ((unsigned long long)bpk << 32);
      const float fa0 = bf2f((unsigned short)apk), fa1 = bf2f((unsigned short)(apk >> 16));
      const float fb0 = bf2f((unsigned short)bpk), fb1 = bf2f((unsigned short)(bpk >> 16));
      A0 *= fa0; h0 = fa0 * h0 + fb0;
      A1 *= fa1; h1 = fa1 * h1 + fb1;
    }
    sA[c * 32 + 2 * dp] = A0;  sA[c * 32 + 2 * dp + 1] = A1;
    sH[c * 32 + 2 * dp] = h0;  sH[c * 32 + 2 * dp + 1] = h1;
    __syncthreads();

    // pass 2: serial carry composition (one lane per d); overwrite sA w/ carry
    if (tid < 32) {
      float hin = carry;
#pragma unroll
      for (int cc = 0; cc < 16; ++cc) {
        const float a  = sA[cc * 32 + tid];
        const float hs = sH[cc * 32 + tid];
        sA[cc * 32 + tid] = hin;
        hin = hs + a * hin;
      }
      carry = hin;
    }
    __syncthreads();

    // pass 3: pure-FMA replay from LDS; write h over the a slot
    float hh0 = sA[c * 32 + 2 * dp];
    float hh1 = sA[c * 32 + 2 * dp + 1];
#pragma unroll
    for (int tl = 0; tl < 16; ++tl) {
      const int t = t0 + tl;
      const unsigned long long ab = sAB[(c * 16 + tl) * 16 + dp];
      const float fa0 = bf2f((unsigned short)ab);
      const float fa1 = bf2f((unsigned short)(ab >> 16));
      const float fb0 = bf2f((unsigned short)(ab >> 32));
      const float fb1 = bf2f((unsigned short)(ab >> 48));
      hh0 = fa0 * hh0 + fb0;
      hh1 = fa1 * hh1 + fb1;
      base[t * 1024 + 512 + du] = (unsigned)f2bf(hh0) | ((unsigned)f2bf(hh1) << 16);
    }
    __syncthreads();   // sAB/sA/sH reused next segment
  }
}

// ---------------------------------------------------------------------------
// RMSNorm in place on bf16 h. One wave per row of 512. (layer 0 only; the
// final rms is fused into the decoder.)
// ---------------------------------------------------------------------------
__global__ __launch_bounds__(256)
void rms_kernel(unsigned short* __restrict__ hb, const float* __restrict__ w) {
  const int wid  = (blockIdx.x * blockDim.x + threadIdx.x) >> 6;
  const int lane = threadIdx.x & 63;
  unsigned short* row = hb + (size_t)wid * 512;
  float v[8];
  float ss = 0.0f;
#pragma unroll
  for (int j = 0; j < 8; j++) { v[j] = bf2f(row[lane + 64 * j]); ss += v[j] * v[j]; }
#pragma unroll
  for (int off = 32; off >= 1; off >>= 1) ss += __shfl_xor(ss, off, 64);
  const float r = rsqrtf(ss * (1.0f / 512.0f) + 1.1920929e-7f);
#pragma unroll
  for (int j = 0; j < 8; j++) {
    const int k = lane + 64 * j;
    row[k] = f2bf(v[j] * r * w[k]);
  }
}

// ---------------------------------------------------------------------------
// Fused final RMSNorm + decoder: normalized row stays in registers (the l1
// rms 32MB write and decoder 32MB re-read vanish; hb is dead afterwards).
// One wave per row; dec_w (32KB f32) is L2-resident.
// ---------------------------------------------------------------------------
__global__ __launch_bounds__(256)
void rms_dec_kernel(const unsigned short* __restrict__ hb,
                    const float* __restrict__ w,
                    const float* __restrict__ dec_w,
                    const float* __restrict__ dec_b,
                    const float* __restrict__ val_w,
                    const float* __restrict__ val_b,
                    float* __restrict__ out) {
  const int row  = (blockIdx.x * blockDim.x + threadIdx.x) >> 6;
  const int lane = threadIdx.x & 63;
  const unsigned short* hr = hb + (size_t)row * 512;
  float v[8];
  float ss = 0.0f;
#pragma unroll
  for (int j = 0; j < 8; j++) { v[j] = bf2f(hr[lane + 64 * j]); ss += v[j] * v[j]; }
#pragma unroll
  for (int off = 32; off >= 1; off >>= 1) ss += __shfl_xor(ss, off, 64);
  const float r = rsqrtf(ss * (1.0f / 512.0f) + 1.1920929e-7f);

  float acc[17];
#pragma unroll
  for (int a = 0; a < 17; a++) acc[a] = 0.0f;
#pragma unroll
  for (int j = 0; j < 8; j++) {
    const int k = lane + 64 * j;
    const float hv = v[j] * r * w[k];
#pragma unroll
    for (int a = 0; a < 16; a++) acc[a] += hv * dec_w[a * 512 + k];
    acc[16] += hv * val_w[k];
  }
#pragma unroll
  for (int a = 0; a < 17; a++) {
#pragma unroll
    for (int off = 32; off >= 1; off >>= 1) acc[a] += __shfl_xor(acc[a], off, 64);
  }
  if (lane == 0) {
    float* logits = out;
    float* values = out + (size_t)MROWS * 16;
#pragma unroll
    for (int a = 0; a < 16; a++) logits[(size_t)row * 16 + a] = acc[a] + dec_b[a];
    values[row] = acc[16] + val_b[0];
  }
}

// ---------------------------------------------------------------------------
__global__ __launch_bounds__(256)
void conv_bf16(const float* __restrict__ in, unsigned short* __restrict__ out, int n4) {
  const int i = blockIdx.x * blockDim.x + threadIdx.x;
  if (i < n4) {
    const float4 v = ((const float4*)in)[i];
    const unsigned long long pack =
        (unsigned long long)f2bf(v.x) |
        ((unsigned long long)f2bf(v.y) << 16) |
        ((unsigned long long)f2bf(v.z) << 32) |
        ((unsigned long long)f2bf(v.w) << 48);
    ((unsigned long long*)out)[i] = pack;
  }
}

// ---------------------------------------------------------------------------
// Workspace layout (bytes) — total 174,587,904 (~166.5 MiB):
//   hg   bf16 [32768,2048] @ 0          (128 MB)  [xb bf16 aliases @0 pre-encoder]
//   hb   bf16 [32768,512]  @ 134217728  (32 MB)
//   wbf  bf16 weights      @ 167772160  (~6.5 MB)
// ---------------------------------------------------------------------------
extern "C" void kernel_launch(void* const* d_in, const int* in_sizes, int n_in,
                              void* d_out, int out_size, void* d_ws, size_t ws_size,
                              hipStream_t stream) {
  const float* x     = (const float*)d_in[0];
  const float* enc_w = (const float*)d_in[1];
  const float* enc_b = (const float*)d_in[2];
  const float* w_hg  = (const float*)d_in[3];
  const float* w_out = (const float*)d_in[4];
  const float* rms_w = (const float*)d_in[5];
  const float* dec_w = (const float*)d_in[6];
  const float* dec_b = (const float*)d_in[7];
  const float* val_w = (const float*)d_in[8];
  const float* val_b = (const float*)d_in[9];
  float* out = (float*)d_out;

  if (ws_size < 174587904u) return;  // fail loudly via absmax, not via fault

  char* ws = (char*)d_ws;
  unsigned short* hg   = (unsigned short*)(ws);
  unsigned short* xb   = (unsigned short*)(ws);               // alias (encoder only)
  unsigned short* hb   = (unsigned short*)(ws + 134217728);
  unsigned short* wenc = (unsigned short*)(ws + 167772160);
  unsigned short* whg  = wenc + 262144;                       // 2 layers x 2048x512
  unsigned short* wout = whg + 2097152;                       // 2 layers x 512x1024

  // bf16 conversions (x + all matmul weights)
  conv_bf16<<<16384, 256, 0, stream>>>(x, xb, 4194304);
  conv_bf16<<<256,   256, 0, stream>>>(enc_w, wenc, 65536);
  conv_bf16<<<2048,  256, 0, stream>>>(w_hg, whg, 524288);
  conv_bf16<<<1024,  256, 0, stream>>>(w_out, wout, 262144);

  // encoder: hb = gelu(x @ enc_w^T + enc_b); 1-D grid, XCD swizzle inside
  gemm_bt<0><<<1024, 256, 0, stream>>>(xb, 512, wenc, 512, 512, enc_b, nullptr, hb);

  for (int l = 0; l < 2; ++l) {
    // hg: paired hidden/gate GEMM + gate transform -> (b | a)
    gemm_hg<<<2048, 256, 0, stream>>>(hb, whg + (size_t)l * 1048576, hg);
    // LDS-cached chunked parallel scan: writes h over the a half
    scan_kernel<<<1024, 256, 0, stream>>>(hg);
    // hb = h(@hg+1024, lda 2048) @ w_out^T + hb  (bf16 residual, in place)
    gemm_bt<2><<<1024, 256, 0, stream>>>(hg + 1024, 2048, wout + (size_t)l * 524288,
                                         512, 1024, nullptr, hb, hb);
    if (l == 0) rms_kernel<<<8192, 256, 0, stream>>>(hb, rms_w);
  }

  // fused final RMSNorm + decoder
  rms_dec_kernel<<<8192, 256, 0, stream>>>(hb, rms_w + 512, dec_w, dec_b,
                                           val_w, val_b, out);
}

// Round 7
// 572.489 us; speedup vs baseline: 1.0984x; 1.0547x over previous
//
#include <hip/hip_runtime.h>
#include <math.h>

// Problem constants: B=32, T=1024, OBS=512, H=512, DI=1024, L=2, A=16
#define MROWS 32768   // B*T
#define T_LEN 1024

typedef __attribute__((ext_vector_type(8))) short bf16x8;
typedef __attribute__((ext_vector_type(4))) float f32x4;

__device__ __forceinline__ unsigned short f2bf(float f) {
  union { float f; unsigned u; } x; x.f = f;
  unsigned r = x.u + 0x7fffu + ((x.u >> 16) & 1u);   // RNE
  return (unsigned short)(r >> 16);
}
__device__ __forceinline__ float bf2f(unsigned short u) {
  union { unsigned u; float f; } x; x.u = ((unsigned)u) << 16; return x.f;
}

__device__ __forceinline__ void gload_lds16(const void* g, void* l) {
  __builtin_amdgcn_global_load_lds(
      (const __attribute__((address_space(1))) void*)g,
      (__attribute__((address_space(3))) void*)l, 16, 0, 0);
}

// fast sigmoid via v_rcp_f32 (1 ulp; invisible under bf16 RNE rounding).
// R14 lesson: 1.0f/(1+e) compiles to the exact-div sequence (~35 VALU/elem).
__device__ __forceinline__ float sigm_neg(float x) {   // sigmoid(-x)
  return __builtin_amdgcn_rcpf(1.0f + __expf(x));
}

#define VMCNT2 asm volatile("s_waitcnt vmcnt(2)" ::: "memory")
#define VMCNT0 asm volatile("s_waitcnt vmcnt(0)" ::: "memory")
// rule #18: inline-asm lgkmcnt needs a following sched_barrier(0) or the
// compiler hoists register-only MFMA above the wait.
#define LGKM0 do { asm volatile("s_waitcnt lgkmcnt(0)" ::: "memory"); \
                   __builtin_amdgcn_sched_barrier(0); } while (0)
#define BAR __builtin_amdgcn_s_barrier()

// ---------------------------------------------------------------------------
// GEMM: C[M,N] = A[M,(lda)] (bf16, K cols used) * B[N,K]^T (bf16), fp32 accum.
// N=512 (4 n-tiles) fixed for both users.
// MODE 0: += bias[n] (f32), exact GELU, write bf16   (encoder)
// MODE 2: += res[m,n] (bf16, may alias outb), write bf16  (out-proj)
// R0's proven m97-structure kernel; XCD-bijective 1-D grid, n-inner.
// ---------------------------------------------------------------------------
template<int MODE>
__global__ __launch_bounds__(256, 2)
void gemm_bt(const unsigned short* __restrict__ A, int lda,
             const unsigned short* __restrict__ B,
             int N, int K,
             const float* __restrict__ bias,
             const unsigned short* res,
             unsigned short* outb)
{
  __shared__ __align__(16) unsigned short sA[128 * 64];
  __shared__ __align__(16) unsigned short sB[128 * 64];
  const int tid  = threadIdx.x;
  const int wave = tid >> 6, lane = tid & 63;
  const int lid = blockIdx.x;
  const int swz = (lid & 7) * ((int)gridDim.x >> 3) + (lid >> 3);
  const int m0 = (swz >> 2) * 128;     // 4 n-tiles, n-inner
  const int n0 = (swz & 3) * 128;
  const int srow   = lane >> 3;                   // row within 8-row group
  const int sslotb = ((lane & 7) ^ srow) * 16;    // swizzled source chunk (bytes)
  const int wm = wave & 1, wn = wave >> 1;
  const int r16 = lane & 15, q = lane >> 4;

  f32x4 acc[4][4];
#pragma unroll
  for (int i = 0; i < 4; i++)
#pragma unroll
    for (int j = 0; j < 4; j++)
#pragma unroll
      for (int e = 0; e < 4; e++) acc[i][j][e] = 0.0f;

  const char* Ab = (const char*)A;
  const char* Bb = (const char*)B;
  char* sAb = (char*)sA;
  char* sBb = (char*)sB;

  for (int kt = 0; kt < K; kt += 64) {
#pragma unroll
    for (int i = 0; i < 4; i++) {
      const int j = wave * 4 + i;
      const int row = j * 8 + srow;
      gload_lds16(Ab + ((size_t)(m0 + row) * lda + kt) * 2 + sslotb, sAb + j * 1024);
      gload_lds16(Bb + ((size_t)(n0 + row) * K   + kt) * 2 + sslotb, sBb + j * 1024);
    }
    __syncthreads();
#pragma unroll
    for (int kh = 0; kh < 2; kh++) {
      bf16x8 af[4], bfr[4];
#pragma unroll
      for (int mt = 0; mt < 4; mt++) {
        const int row = wm * 64 + mt * 16 + r16;
        af[mt] = *(const bf16x8*)(sAb + row * 128 + ((((kh << 2) | q) ^ (row & 7)) * 16));
      }
#pragma unroll
      for (int nt = 0; nt < 4; nt++) {
        const int row = wn * 64 + nt * 16 + r16;
        bfr[nt] = *(const bf16x8*)(sBb + row * 128 + ((((kh << 2) | q) ^ (row & 7)) * 16));
      }
#pragma unroll
      for (int mt = 0; mt < 4; mt++)
#pragma unroll
        for (int nt = 0; nt < 4; nt++)
          acc[mt][nt] = __builtin_amdgcn_mfma_f32_16x16x32_bf16(af[mt], bfr[nt], acc[mt][nt], 0, 0, 0);
    }
    __syncthreads();
  }

  // epilogue; C/D layout: n = lane&15, m = (lane>>4)*4 + r
#pragma unroll
  for (int mt = 0; mt < 4; mt++) {
#pragma unroll
    for (int nt = 0; nt < 4; nt++) {
#pragma unroll
      for (int r = 0; r < 4; r++) {
        const int m = m0 + wm * 64 + mt * 16 + q * 4 + r;
        const int n = n0 + wn * 64 + nt * 16 + r16;
        const size_t idx = (size_t)m * N + n;
        float v = acc[mt][nt][r];
        if (MODE == 0) {
          v += bias[n];
          v = 0.5f * v * (1.0f + erff(v * 0.70710678118654752f));
        } else if (MODE == 2) {
          v += bf2f(res[idx]);
        }
        outb[idx] = f2bf(v);
      }
    }
  }
}

// ---------------------------------------------------------------------------
// hg GEMM, R17: faithful port of the verified 256^2 8-phase template (m201)
// to the paired hidden/gate shape. BM=256, BN=128hid+128gate, BK=64, 512
// threads / 8 waves (2M x 4N); each wave owns 128m x (32hid+32gate, SAME d
// range) so the fused epilogue b=(1-a)*G survives. K=512 -> 8 K-tiles,
// iteration = 2 K-tiles = 8 phases x 16 MFMA.
//   phase = { ds_read 8xb128 | stage 2xgload_lds ; s_barrier(no drain);
//             lgkmcnt(0)+sched_barrier; setprio(1) 16 MFMA setprio(0);
//             s_barrier }
// Counted vmcnt(2) ONLY at phases 1 and 5 (never 0 mid-loop, T4/m218):
// phases 1-4 stage tile 2t+1 -> buf1 (read ph5-8, same iter); phases 5-8
// stage tile 2t+2 -> buf0 (read next iter ph1-4). WAR: each buffer staged
// only after its previous reader's last barrier. LDS = 2 x (A 32K + Bh 16K
// + Bg 16K) = 128 KiB, buffers fixed by tile parity. Same proven XOR
// swizzle (slot = chunk ^ (row&7), 0 conflicts measured). Accumulation
// order (tile, kh) identical to R16 -> bit-identical numerics.
// ---------------------------------------------------------------------------
__global__ __launch_bounds__(512, 2)
void gemm_hg8(const unsigned short* __restrict__ A,    // hb [M,512]
              const unsigned short* __restrict__ B,    // whg layer [2048,512]
              unsigned short* __restrict__ outb)       // hg [M,2048]
{
  __shared__ __align__(16) char smem[131072];  // buf p @ p*65536: [A 32K][Bh 16K][Bg 16K]
  const int tid  = threadIdx.x;
  const int wave = tid >> 6, lane = tid & 63;
  const int lid = blockIdx.x;
  const int swz = (lid & 7) * 128 + (lid >> 3);   // nwg=1024, XCD-bijective
  const int m0  = (swz >> 3) * 256;               // 128 m-tiles
  const int nh0 = (swz & 7) * 128;                // d-panel (n-inner: A L2-hot)
  const int wm = wave >> 2, wn = wave & 3;
  const int r16 = lane & 15, q4 = lane >> 4;

  // staging geometry: quantum = 8KB = 64 rows x 8 chunks; 1 gload/thread
  const int srow   = tid >> 3;                    // 0..63
  const int sslotb = ((tid & 7) ^ (srow & 7)) * 16;
  const int sldso  = tid * 16;                    // linear LDS dest in quantum

  // read-side slots (row&7 == r16&7 for all fragment rows)
  const int slot0 = ((q4)     ^ (r16 & 7)) * 16;  // kh=0
  const int slot1 = ((4 | q4) ^ (r16 & 7)) * 16;  // kh=1

  const char* Ab = (const char*)A;
  const char* Bb = (const char*)B;

  f32x4 acc[8][4];   // [m-frag][0,1=hid 2,3=gate]
#pragma unroll
  for (int i = 0; i < 8; i++)
#pragma unroll
    for (int j = 0; j < 4; j++)
#pragma unroll
      for (int e = 0; e < 4; e++) acc[i][j][e] = 0.0f;

  // stage quanta 2*qp, 2*qp+1 of K-tile u into buf[u&1]
  auto stage2 = [&](int u, int qp) {
    char* base = smem + (u & 1) * 65536;
    const int kt2 = u << 7;                       // byte col offset = u*64*2
#pragma unroll
    for (int i = 0; i < 2; ++i) {
      const int qq = qp * 2 + i;                  // 0..7
      if (qq < 4) {        // A rows qq*64..+63
        gload_lds16(Ab + (size_t)(m0 + qq * 64 + srow) * 1024 + kt2 + sslotb,
                    base + qq * 8192 + sldso);
      } else if (qq < 6) { // B hidden rows
        gload_lds16(Bb + (size_t)(nh0 + (qq - 4) * 64 + srow) * 1024 + kt2 + sslotb,
                    base + 32768 + (qq - 4) * 8192 + sldso);
      } else {             // B gate rows
        gload_lds16(Bb + (size_t)(1024 + nh0 + (qq - 6) * 64 + srow) * 1024 + kt2 + sslotb,
                    base + 49152 + (qq - 6) * 8192 + sldso);
      }
    }
  };

  auto lda_frags = [&](const char* base, int kh, int mh,
                       bf16x8 af[4], bf16x8 bh[2], bf16x8 bg[2]) {
    const int slot = kh ? slot1 : slot0;
#pragma unroll
    for (int mt = 0; mt < 4; ++mt) {
      const int row = wm * 128 + mh * 64 + mt * 16 + r16;
      af[mt] = *(const bf16x8*)(base + row * 128 + slot);
    }
#pragma unroll
    for (int nt = 0; nt < 2; ++nt) {
      const int row = wn * 32 + nt * 16 + r16;
      bh[nt] = *(const bf16x8*)(base + 32768 + row * 128 + slot);
      bg[nt] = *(const bf16x8*)(base + 49152 + row * 128 + slot);
    }
  };

  auto mfma16 = [&](int mh, bf16x8 af[4], bf16x8 bh[2], bf16x8 bg[2]) {
    __builtin_amdgcn_s_setprio(1);
#pragma unroll
    for (int mt = 0; mt < 4; ++mt) {
      const int MT = mh * 4 + mt;
      acc[MT][0] = __builtin_amdgcn_mfma_f32_16x16x32_bf16(af[mt], bh[0], acc[MT][0], 0, 0, 0);
      acc[MT][1] = __builtin_amdgcn_mfma_f32_16x16x32_bf16(af[mt], bh[1], acc[MT][1], 0, 0, 0);
      acc[MT][2] = __builtin_amdgcn_mfma_f32_16x16x32_bf16(af[mt], bg[0], acc[MT][2], 0, 0, 0);
      acc[MT][3] = __builtin_amdgcn_mfma_f32_16x16x32_bf16(af[mt], bg[1], acc[MT][3], 0, 0, 0);
    }
    __builtin_amdgcn_s_setprio(0);
  };

  // prologue: tile 0 -> buf0, full drain once
#pragma unroll
  for (int qp = 0; qp < 4; ++qp) stage2(0, qp);
  VMCNT0; BAR;

  for (int t = 0; t < 4; ++t) {                   // NT=8, 2 K-tiles/iter
    const int u1 = 2 * t + 1;
    const char* b0 = smem;
    const char* b1 = smem + 65536;
    bf16x8 af[4], bh[2], bg[2];
    const bool more = (t < 3);

    // phases 1-4: compute tile 2t (buf0); stage tile 2t+1 -> buf1
#pragma unroll
    for (int pi = 0; pi < 4; ++pi) {
      const int kh = pi >> 1, mh = pi & 1;
      if (pi == 0) {
        stage2(u1, 0);
        VMCNT2;              // tile 2t's 8 loads (older) done; 2 stay in flight
        BAR;
        lda_frags(b0, kh, mh, af, bh, bg);
      } else {
        lda_frags(b0, kh, mh, af, bh, bg);
        stage2(u1, pi);
        BAR;
      }
      LGKM0;
      mfma16(mh, af, bh, bg);
      BAR;
    }

    // phases 5-8: compute tile 2t+1 (buf1); stage tile 2t+2 -> buf0
#pragma unroll
    for (int pi = 0; pi < 4; ++pi) {
      const int kh = pi >> 1, mh = pi & 1;
      if (pi == 0) {
        if (more) { stage2(u1 + 1, 0); VMCNT2; } else { VMCNT0; }
        BAR;
        lda_frags(b1, kh, mh, af, bh, bg);
      } else {
        lda_frags(b1, kh, mh, af, bh, bg);
        if (more) stage2(u1 + 1, pi);
        BAR;
      }
      LGKM0;
      mfma16(mh, af, bh, bg);
      BAR;
    }
  }

  // epilogue: emit b (hidden slot) and a (gate slot)
#pragma unroll
  for (int MT = 0; MT < 8; ++MT) {
#pragma unroll
    for (int nf = 0; nf < 2; ++nf) {
#pragma unroll
      for (int r = 0; r < 4; ++r) {
        const int m = m0 + wm * 128 + MT * 16 + q4 * 4 + r;
        const int d = nh0 + wn * 32 + nf * 16 + r16;
        const float vh = acc[MT][nf][r];
        const float vg = acc[MT][nf + 2][r];
        const float G = (vh >= 0.0f) ? (vh + 0.5f) : sigm_neg(-vh);
        const float a = sigm_neg(vg);
        const float b = (1.0f - a) * G;
        const size_t base = (size_t)m * 2048 + d;
        outb[base]        = f2bf(b);
        outb[base + 1024] = f2bf(a);
      }
    }
  }
}

// ---------------------------------------------------------------------------
// minGRU chunked parallel scan, LDS-cache variant, pure load+FMA pass 1.
// hg holds b (hidden slot) and a (gate slot) from gemm_hg8's epilogue.
// h_t = a_t*h_{t-1} + b_t. 4 segments of 256; cache 32KB+4KB -> 4 blocks/CU.
// ---------------------------------------------------------------------------
__global__ __launch_bounds__(256)
void scan_kernel(unsigned short* hg) {
  __shared__ unsigned long long sAB[256 * 16];   // [t_local][dp]: lo=a-pair, hi=b-pair
  __shared__ float sA[16 * 32];                  // [chunk][d]: A-prod, then carry
  __shared__ float sH[16 * 32];                  // [chunk][d]: local scan sum
  const int b  = blockIdx.x >> 5;      // batch
  const int dg = blockIdx.x & 31;      // 32-d group
  const int tid = threadIdx.x;
  const int c  = tid >> 4;             // chunk 0..15
  const int dp = tid & 15;             // d-pair 0..15
  unsigned int* base = (unsigned int*)(hg + (size_t)b * T_LEN * 2048);
  const int du = dg * 16 + dp;         // u32 col of this thread's d-pair

  float carry = 0.0f;                  // per-d carry, lanes tid<32 only

  for (int seg = 0; seg < 4; ++seg) {
    const int t0 = seg * 256 + c * 16;

    // pass 1: read (b, a), cache packed, accumulate chunk summary
    float A0 = 1.0f, A1 = 1.0f, h0 = 0.0f, h1 = 0.0f;
#pragma unroll
    for (int tl = 0; tl < 16; ++tl) {
      const int t = t0 + tl;
      const unsigned bpk = base[t * 1024 + du];        // b pair (hidden slot)
      const unsigned apk = base[t * 1024 + 512 + du];  // a pair (gate slot)
      sAB[(c * 16 + tl) * 16 + dp] =
          (unsigned long long)apk | ((unsigned long long)bpk << 32);
      const float fa0 = bf2f((unsigned short)apk), fa1 = bf2f((unsigned short)(apk >> 16));
      const float fb0 = bf2f((unsigned short)bpk), fb1 = bf2f((unsigned short)(bpk >> 16));
      A0 *= fa0; h0 = fa0 * h0 + fb0;
      A1 *= fa1; h1 = fa1 * h1 + fb1;
    }
    sA[c * 32 + 2 * dp] = A0;  sA[c * 32 + 2 * dp + 1] = A1;
    sH[c * 32 + 2 * dp] = h0;  sH[c * 32 + 2 * dp + 1] = h1;
    __syncthreads();

    // pass 2: serial carry composition (one lane per d); overwrite sA w/ carry
    if (tid < 32) {
      float hin = carry;
#pragma unroll
      for (int cc = 0; cc < 16; ++cc) {
        const float a  = sA[cc * 32 + tid];
        const float hs = sH[cc * 32 + tid];
        sA[cc * 32 + tid] = hin;
        hin = hs + a * hin;
      }
      carry = hin;
    }
    __syncthreads();

    // pass 3: pure-FMA replay from LDS; write h over the a slot
    float hh0 = sA[c * 32 + 2 * dp];
    float hh1 = sA[c * 32 + 2 * dp + 1];
#pragma unroll
    for (int tl = 0; tl < 16; ++tl) {
      const int t = t0 + tl;
      const unsigned long long ab = sAB[(c * 16 + tl) * 16 + dp];
      const float fa0 = bf2f((unsigned short)ab);
      const float fa1 = bf2f((unsigned short)(ab >> 16));
      const float fb0 = bf2f((unsigned short)(ab >> 32));
      const float fb1 = bf2f((unsigned short)(ab >> 48));
      hh0 = fa0 * hh0 + fb0;
      hh1 = fa1 * hh1 + fb1;
      base[t * 1024 + 512 + du] = (unsigned)f2bf(hh0) | ((unsigned)f2bf(hh1) << 16);
    }
    __syncthreads();   // sAB/sA/sH reused next segment
  }
}

// ---------------------------------------------------------------------------
// RMSNorm in place on bf16 h. One wave per row of 512. (layer 0 only)
// ---------------------------------------------------------------------------
__global__ __launch_bounds__(256)
void rms_kernel(unsigned short* __restrict__ hb, const float* __restrict__ w) {
  const int wid  = (blockIdx.x * blockDim.x + threadIdx.x) >> 6;
  const int lane = threadIdx.x & 63;
  unsigned short* row = hb + (size_t)wid * 512;
  float v[8];
  float ss = 0.0f;
#pragma unroll
  for (int j = 0; j < 8; j++) { v[j] = bf2f(row[lane + 64 * j]); ss += v[j] * v[j]; }
#pragma unroll
  for (int off = 32; off >= 1; off >>= 1) ss += __shfl_xor(ss, off, 64);
  const float r = rsqrtf(ss * (1.0f / 512.0f) + 1.1920929e-7f);
#pragma unroll
  for (int j = 0; j < 8; j++) {
    const int k = lane + 64 * j;
    row[k] = f2bf(v[j] * r * w[k]);
  }
}

// ---------------------------------------------------------------------------
// Fused final RMSNorm + decoder (l1 rms write + decoder re-read eliminated).
// ---------------------------------------------------------------------------
__global__ __launch_bounds__(256)
void rms_dec_kernel(const unsigned short* __restrict__ hb,
                    const float* __restrict__ w,
                    const float* __restrict__ dec_w,
                    const float* __restrict__ dec_b,
                    const float* __restrict__ val_w,
                    const float* __restrict__ val_b,
                    float* __restrict__ out) {
  const int row  = (blockIdx.x * blockDim.x + threadIdx.x) >> 6;
  const int lane = threadIdx.x & 63;
  const unsigned short* hr = hb + (size_t)row * 512;
  float v[8];
  float ss = 0.0f;
#pragma unroll
  for (int j = 0; j < 8; j++) { v[j] = bf2f(hr[lane + 64 * j]); ss += v[j] * v[j]; }
#pragma unroll
  for (int off = 32; off >= 1; off >>= 1) ss += __shfl_xor(ss, off, 64);
  const float r = rsqrtf(ss * (1.0f / 512.0f) + 1.1920929e-7f);

  float acc[17];
#pragma unroll
  for (int a = 0; a < 17; a++) acc[a] = 0.0f;
#pragma unroll
  for (int j = 0; j < 8; j++) {
    const int k = lane + 64 * j;
    const float hv = v[j] * r * w[k];
#pragma unroll
    for (int a = 0; a < 16; a++) acc[a] += hv * dec_w[a * 512 + k];
    acc[16] += hv * val_w[k];
  }
#pragma unroll
  for (int a = 0; a < 17; a++) {
#pragma unroll
    for (int off = 32; off >= 1; off >>= 1) acc[a] += __shfl_xor(acc[a], off, 64);
  }
  if (lane == 0) {
    float* logits = out;
    float* values = out + (size_t)MROWS * 16;
#pragma unroll
    for (int a = 0; a < 16; a++) logits[(size_t)row * 16 + a] = acc[a] + dec_b[a];
    values[row] = acc[16] + val_b[0];
  }
}

// ---------------------------------------------------------------------------
__global__ __launch_bounds__(256)
void conv_bf16(const float* __restrict__ in, unsigned short* __restrict__ out, int n4) {
  const int i = blockIdx.x * blockDim.x + threadIdx.x;
  if (i < n4) {
    const float4 v = ((const float4*)in)[i];
    const unsigned long long pack =
        (unsigned long long)f2bf(v.x) |
        ((unsigned long long)f2bf(v.y) << 16) |
        ((unsigned long long)f2bf(v.z) << 32) |
        ((unsigned long long)f2bf(v.w) << 48);
    ((unsigned long long*)out)[i] = pack;
  }
}

// ---------------------------------------------------------------------------
// Workspace layout (bytes) — total 174,587,904 (~166.5 MiB):
//   hg   bf16 [32768,2048] @ 0          (128 MB)  [xb bf16 aliases @0 pre-encoder]
//   hb   bf16 [32768,512]  @ 134217728  (32 MB)
//   wbf  bf16 weights      @ 167772160  (~6.5 MB)
// ---------------------------------------------------------------------------
extern "C" void kernel_launch(void* const* d_in, const int* in_sizes, int n_in,
                              void* d_out, int out_size, void* d_ws, size_t ws_size,
                              hipStream_t stream) {
  const float* x     = (const float*)d_in[0];
  const float* enc_w = (const float*)d_in[1];
  const float* enc_b = (const float*)d_in[2];
  const float* w_hg  = (const float*)d_in[3];
  const float* w_out = (const float*)d_in[4];
  const float* rms_w = (const float*)d_in[5];
  const float* dec_w = (const float*)d_in[6];
  const float* dec_b = (const float*)d_in[7];
  const float* val_w = (const float*)d_in[8];
  const float* val_b = (const float*)d_in[9];
  float* out = (float*)d_out;

  if (ws_size < 174587904u) return;  // fail loudly via absmax, not via fault

  char* ws = (char*)d_ws;
  unsigned short* hg   = (unsigned short*)(ws);
  unsigned short* xb   = (unsigned short*)(ws);               // alias (encoder only)
  unsigned short* hb   = (unsigned short*)(ws + 134217728);
  unsigned short* wenc = (unsigned short*)(ws + 167772160);
  unsigned short* whg  = wenc + 262144;                       // 2 layers x 2048x512
  unsigned short* wout = whg + 2097152;                       // 2 layers x 512x1024

  // bf16 conversions (x + all matmul weights)
  conv_bf16<<<16384, 256, 0, stream>>>(x, xb, 4194304);
  conv_bf16<<<256,   256, 0, stream>>>(enc_w, wenc, 65536);
  conv_bf16<<<2048,  256, 0, stream>>>(w_hg, whg, 524288);
  conv_bf16<<<1024,  256, 0, stream>>>(w_out, wout, 262144);

  // encoder: hb = gelu(x @ enc_w^T + enc_b); 1-D grid, XCD swizzle inside
  gemm_bt<0><<<1024, 256, 0, stream>>>(xb, 512, wenc, 512, 512, enc_b, nullptr, hb);

  for (int l = 0; l < 2; ++l) {
    // hg: 8-phase paired hidden/gate GEMM + gate transform -> (b | a)
    gemm_hg8<<<1024, 512, 0, stream>>>(hb, whg + (size_t)l * 1048576, hg);
    // LDS-cached chunked parallel scan: writes h over the a half
    scan_kernel<<<1024, 256, 0, stream>>>(hg);
    // hb = h(@hg+1024, lda 2048) @ w_out^T + hb  (bf16 residual, in place)
    gemm_bt<2><<<1024, 256, 0, stream>>>(hg + 1024, 2048, wout + (size_t)l * 524288,
                                         512, 1024, nullptr, hb, hb);
    if (l == 0) rms_kernel<<<8192, 256, 0, stream>>>(hb, rms_w);
  }

  // fused final RMSNorm + decoder
  rms_dec_kernel<<<8192, 256, 0, stream>>>(hb, rms_w + 512, dec_w, dec_b,
                                           val_w, val_b, out);
}